// Round 1
// baseline (452.172 us; speedup 1.0000x reference)
//
#include <hip/hip_runtime.h>
#include <math.h>

// AttentionPooling: scores = tanh(x@W1+b1)@W2+b2; segment softmax over sorted
// `batch`; out[g,:] = sum_i w_i * x[i,:].
// N = in_sizes[1] (200000), D = 256, H = 128, G = out_size/256 (512).

#define TILE_M 128
#define BK 32
#define APITCH 132   // 128 + 4: keeps float4 LDS reads 16B-aligned, breaks bank stride

__global__ __launch_bounds__(256)
void scores_kernel(const float* __restrict__ x, const float* __restrict__ W1,
                   const float* __restrict__ b1, const float* __restrict__ W2,
                   const float* __restrict__ b2, float* __restrict__ scores, int N)
{
    __shared__ float As[BK][APITCH];   // transposed x tile: As[k][row]
    __shared__ float Bs[BK][128];      // W1 tile: Bs[k][col]

    const int tid = threadIdx.x;       // 0..255
    const int tx = tid & 15;           // col group (8 cols each)
    const int ty = tid >> 4;           // row group (8 rows each)
    const int rowBase = blockIdx.x * TILE_M;

    float acc[8][8];
#pragma unroll
    for (int i = 0; i < 8; ++i)
#pragma unroll
        for (int j = 0; j < 8; ++j) acc[i][j] = 0.f;

    for (int k0 = 0; k0 < 256; k0 += BK) {
        // ---- stage A (x tile, transposed into LDS) ----
#pragma unroll
        for (int i = 0; i < 4; ++i) {
            int idx = tid + 256 * i;      // 0..1023
            int r   = idx >> 3;           // 0..127
            int kk  = (idx & 7) << 2;     // 0,4,...,28
            int row = rowBase + r;
            float4 v = make_float4(0.f, 0.f, 0.f, 0.f);
            if (row < N) v = *(const float4*)(x + (size_t)row * 256 + k0 + kk);
            As[kk + 0][r] = v.x; As[kk + 1][r] = v.y;
            As[kk + 2][r] = v.z; As[kk + 3][r] = v.w;
        }
        // ---- stage B (W1 tile) ----
#pragma unroll
        for (int i = 0; i < 4; ++i) {
            int idx = tid + 256 * i;      // 0..1023
            int kk  = idx >> 5;           // 0..31
            int c   = (idx & 31) << 2;    // 0..124
            *(float4*)&Bs[kk][c] = *(const float4*)(W1 + (size_t)(k0 + kk) * 128 + c);
        }
        __syncthreads();

#pragma unroll 8
        for (int kk = 0; kk < BK; ++kk) {
            float a[8], b[8];
            *(float4*)&a[0] = *(const float4*)&As[kk][ty * 8];
            *(float4*)&a[4] = *(const float4*)&As[kk][ty * 8 + 4];
            *(float4*)&b[0] = *(const float4*)&Bs[kk][tx * 8];
            *(float4*)&b[4] = *(const float4*)&Bs[kk][tx * 8 + 4];
#pragma unroll
            for (int i = 0; i < 8; ++i)
#pragma unroll
                for (int j = 0; j < 8; ++j)
                    acc[i][j] = fmaf(a[i], b[j], acc[i][j]);
        }
        __syncthreads();
    }

    // ---- epilogue: tanh, dot with W2, reduce across the 16 col-threads ----
    float b1v[8], w2v[8];
#pragma unroll
    for (int j = 0; j < 8; ++j) {
        b1v[j] = b1[tx * 8 + j];
        w2v[j] = W2[tx * 8 + j];
    }
    const float bias2 = b2[0];

#pragma unroll
    for (int i = 0; i < 8; ++i) {
        float s = 0.f;
#pragma unroll
        for (int j = 0; j < 8; ++j)
            s += tanhf(acc[i][j] + b1v[j]) * w2v[j];
        // lanes with same ty are 16 consecutive lanes in a wave -> width-16 butterfly
        for (int off = 8; off > 0; off >>= 1)
            s += __shfl_xor(s, off, 16);
        if (tx == 0) {
            int row = rowBase + ty * 8 + i;
            if (row < N) scores[row] = s + bias2;
        }
    }
}

__device__ __forceinline__ int lower_bound_dev(const int* __restrict__ b, int n, int v)
{
    int lo = 0, hi = n;
    while (lo < hi) {
        int mid = (lo + hi) >> 1;
        if (b[mid] < v) lo = mid + 1; else hi = mid;
    }
    return lo;
}

__global__ __launch_bounds__(256)
void segpool_kernel(const float* __restrict__ x, const int* __restrict__ batch,
                    const float* __restrict__ scores, float* __restrict__ out, int N)
{
    const int g = blockIdx.x;
    const int tid = threadIdx.x;      // == feature dim d (D=256)

    __shared__ float red[256];
    __shared__ float wbuf[256];
    __shared__ int se[2];

    if (tid < 2) se[tid] = lower_bound_dev(batch, N, g + tid);
    __syncthreads();
    const int start = se[0], end = se[1];

    // pass 1: segment max
    float m = -INFINITY;
    for (int i = start + tid; i < end; i += 256) m = fmaxf(m, scores[i]);
    red[tid] = m; __syncthreads();
    for (int s2 = 128; s2 > 0; s2 >>= 1) {
        if (tid < s2) red[tid] = fmaxf(red[tid], red[tid + s2]);
        __syncthreads();
    }
    m = red[0];
    __syncthreads();

    // pass 2: denom
    float ssum = 0.f;
    for (int i = start + tid; i < end; i += 256) ssum += expf(scores[i] - m);
    red[tid] = ssum; __syncthreads();
    for (int s2 = 128; s2 > 0; s2 >>= 1) {
        if (tid < s2) red[tid] += red[tid + s2];
        __syncthreads();
    }
    const float denom = red[0];
    const float inv = (denom > 0.f) ? 1.f / denom : 0.f;

    // pass 3: weighted sum over the segment, thread d owns out[g][d]
    float acc = 0.f;
    for (int base = start; base < end; base += 256) {
        int cnt = min(256, end - base);
        __syncthreads();
        if (tid < cnt) wbuf[tid] = expf(scores[base + tid] - m) * inv;
        __syncthreads();
#pragma unroll 4
        for (int j = 0; j < cnt; ++j)
            acc = fmaf(wbuf[j], x[(size_t)(base + j) * 256 + tid], acc);
    }
    out[(size_t)g * 256 + tid] = acc;
}

extern "C" void kernel_launch(void* const* d_in, const int* in_sizes, int n_in,
                              void* d_out, int out_size, void* d_ws, size_t ws_size,
                              hipStream_t stream) {
    const float* x     = (const float*)d_in[0];
    const int*   batch = (const int*)  d_in[1];
    const float* W1    = (const float*)d_in[2];
    const float* b1    = (const float*)d_in[3];
    const float* W2    = (const float*)d_in[4];
    const float* b2    = (const float*)d_in[5];
    float* out = (float*)d_out;

    const int N = in_sizes[1];          // 200000
    const int G = out_size / 256;       // 512

    float* scores = (float*)d_ws;       // N floats = 800 KB scratch

    const int mblocks = (N + TILE_M - 1) / TILE_M;
    scores_kernel<<<mblocks, 256, 0, stream>>>(x, W1, b1, W2, b2, scores, N);
    segpool_kernel<<<G, 256, 0, stream>>>(x, batch, scores, out, N);
}

// Round 3
// 440.706 us; speedup vs baseline: 1.0260x; 1.0260x over previous
//
#include <hip/hip_runtime.h>
#include <math.h>

// AttentionPooling: scores = tanh(x@W1+b1)@W2+b2; segment softmax over sorted
// `batch`; out[g,:] = sum_i w_i * x[i,:].
// N = in_sizes[1] (200000), D = 256, H = 128, G = out_size/256 (512).

#define TILE_M 128
#define BK 32
#define APITCH 132   // 128 + 4: keeps float4 LDS reads 16B-aligned

__global__ __launch_bounds__(256)
void scores_kernel(const float* __restrict__ x, const float* __restrict__ W1,
                   const float* __restrict__ b1, const float* __restrict__ W2,
                   const float* __restrict__ b2, float* __restrict__ scores, int N)
{
    __shared__ float As[BK][APITCH];   // transposed x tile: As[k][row]
    __shared__ float Bs[BK][128];      // W1 tile, XOR-swizzled float4 columns

    const int tid = threadIdx.x;       // 0..255
    const int tx = tid & 15;           // col group (8 cols each)
    const int ty = tid >> 4;           // row group (8 rows each)
    const int rowBase = blockIdx.x * TILE_M;

    float acc[8][8];
#pragma unroll
    for (int i = 0; i < 8; ++i)
#pragma unroll
        for (int j = 0; j < 8; ++j) acc[i][j] = 0.f;

    for (int k0 = 0; k0 < 256; k0 += BK) {
        // ---- stage A (x tile, transposed into LDS) ----
#pragma unroll
        for (int i = 0; i < 4; ++i) {
            int idx = tid + 256 * i;      // 0..1023
            int r   = idx >> 3;           // 0..127
            int kk  = (idx & 7) << 2;     // 0,4,...,28
            int row = rowBase + r;
            float4 v = make_float4(0.f, 0.f, 0.f, 0.f);
            if (row < N) v = *(const float4*)(x + (size_t)row * 256 + k0 + kk);
            As[kk + 0][r] = v.x; As[kk + 1][r] = v.y;
            As[kk + 2][r] = v.z; As[kk + 3][r] = v.w;
        }
        // ---- stage B (W1 tile), xor-swizzle float4 index: phys = i ^ (i>>3) ----
#pragma unroll
        for (int i = 0; i < 4; ++i) {
            int idx = tid + 256 * i;      // 0..1023
            int kk  = idx >> 5;           // 0..31
            int c4  = idx & 31;           // logical float4 column 0..31
            int p4  = c4 ^ (c4 >> 3);     // swizzled physical float4 slot
            *(float4*)&Bs[kk][p4 << 2] =
                *(const float4*)(W1 + (size_t)(k0 + kk) * 128 + (c4 << 2));
        }
        __syncthreads();

#pragma unroll 8
        for (int kk = 0; kk < BK; ++kk) {
            float a[8], b[8];
            *(float4*)&a[0] = *(const float4*)&As[kk][ty * 8];
            *(float4*)&a[4] = *(const float4*)&As[kk][ty * 8 + 4];
            // logical float4 slots 2tx and 2tx+1:
            //   phys(2tx)   = 2tx ^ (tx>>2)        = p0
            //   phys(2tx+1) = (2tx+1) ^ (tx>>2)    = p0 ^ 1   (NOT p0+1!)
            int p0 = (tx * 2) ^ (tx >> 2);
            int p1 = p0 ^ 1;
            *(float4*)&b[0] = *(const float4*)&Bs[kk][p0 << 2];
            *(float4*)&b[4] = *(const float4*)&Bs[kk][p1 << 2];
#pragma unroll
            for (int i = 0; i < 8; ++i)
#pragma unroll
                for (int j = 0; j < 8; ++j)
                    acc[i][j] = fmaf(a[i], b[j], acc[i][j]);
        }
        __syncthreads();
    }

    // ---- epilogue: tanh, dot with W2, reduce across the 16 col-threads ----
    // acc[i][j] is logical col tx*8+j; j<4 came from slot 2tx (phys p0),
    // j>=4 from slot 2tx+1 (phys p0^1) — mapping below unchanged.
    float b1v[8], w2v[8];
#pragma unroll
    for (int j = 0; j < 8; ++j) {
        b1v[j] = b1[tx * 8 + j];
        w2v[j] = W2[tx * 8 + j];
    }
    const float bias2 = b2[0];

#pragma unroll
    for (int i = 0; i < 8; ++i) {
        float s = 0.f;
#pragma unroll
        for (int j = 0; j < 8; ++j)
            s += tanhf(acc[i][j] + b1v[j]) * w2v[j];
        for (int off = 8; off > 0; off >>= 1)
            s += __shfl_xor(s, off, 16);
        if (tx == 0) {
            int row = rowBase + ty * 8 + i;
            if (row < N) scores[row] = s + bias2;
        }
    }
}

__device__ __forceinline__ int lower_bound_dev(const int* __restrict__ b, int n, int v)
{
    int lo = 0, hi = n;
    while (lo < hi) {
        int mid = (lo + hi) >> 1;
        if (b[mid] < v) lo = mid + 1; else hi = mid;
    }
    return lo;
}

// One 1024-thread block per segment. thread = (rslot 0..15, fidx 0..63);
// 16 rows in flight, float4 per lane (wave = 1KB contiguous row slice).
__global__ __launch_bounds__(1024)
void segpool_kernel(const float* __restrict__ x, const int* __restrict__ batch,
                    const float* __restrict__ scores, float* __restrict__ out, int N)
{
    const int g = blockIdx.x;
    const int tid = threadIdx.x;        // 0..1023
    const int fidx  = tid & 63;         // feature group (4 floats)
    const int rslot = tid >> 6;         // 0..15

    __shared__ int se[2];
    __shared__ float sred[1024];        // reductions + weight chunk buffer
    __shared__ float4 rbuf[16][64];     // rowslot partials

    if (tid < 2) se[tid] = lower_bound_dev(batch, N, g + tid);
    __syncthreads();
    const int start = se[0], end = se[1];

    // pass 1: segment max
    float m = -INFINITY;
    for (int i = start + tid; i < end; i += 1024) m = fmaxf(m, scores[i]);
#pragma unroll
    for (int off = 32; off > 0; off >>= 1) m = fmaxf(m, __shfl_xor(m, off, 64));
    if ((tid & 63) == 0) sred[tid >> 6] = m;
    __syncthreads();
    if (tid < 16) {
        float v = sred[tid];
#pragma unroll
        for (int off = 8; off > 0; off >>= 1) v = fmaxf(v, __shfl_xor(v, off, 16));
        if (tid == 0) sred[0] = v;
    }
    __syncthreads();
    m = sred[0];
    __syncthreads();

    // pass 2: denom
    float ssum = 0.f;
    for (int i = start + tid; i < end; i += 1024) ssum += expf(scores[i] - m);
#pragma unroll
    for (int off = 32; off > 0; off >>= 1) ssum += __shfl_xor(ssum, off, 64);
    if ((tid & 63) == 0) sred[tid >> 6] = ssum;
    __syncthreads();
    if (tid < 16) {
        float v = sred[tid];
#pragma unroll
        for (int off = 8; off > 0; off >>= 1) v += __shfl_xor(v, off, 16);
        if (tid == 0) sred[0] = v;
    }
    __syncthreads();
    const float denom = sred[0];
    const float inv = (denom > 0.f) ? 1.f / denom : 0.f;

    // pass 3: weighted sum; chunk weights into LDS, 16 rows in flight
    float4 acc = make_float4(0.f, 0.f, 0.f, 0.f);
    for (int base = start; base < end; base += 1024) {
        int cnt = min(1024, end - base);
        __syncthreads();
        if (tid < cnt) sred[tid] = expf(scores[base + tid] - m) * inv;
        __syncthreads();
#pragma unroll 2
        for (int j = rslot; j < cnt; j += 16) {
            float w = sred[j];
            float4 v = *(const float4*)(x + (size_t)(base + j) * 256 + fidx * 4);
            acc.x = fmaf(w, v.x, acc.x);
            acc.y = fmaf(w, v.y, acc.y);
            acc.z = fmaf(w, v.z, acc.z);
            acc.w = fmaf(w, v.w, acc.w);
        }
    }

    // reduce 16 rowslot partials per feature group
    rbuf[rslot][fidx] = acc;
    __syncthreads();
#pragma unroll
    for (int s = 8; s > 0; s >>= 1) {
        if (rslot < s) {
            float4 o = rbuf[rslot + s][fidx];
            acc.x += o.x; acc.y += o.y; acc.z += o.z; acc.w += o.w;
            rbuf[rslot][fidx] = acc;
        }
        __syncthreads();
    }
    if (rslot == 0)
        ((float4*)out)[(size_t)g * 64 + fidx] = acc;
}

extern "C" void kernel_launch(void* const* d_in, const int* in_sizes, int n_in,
                              void* d_out, int out_size, void* d_ws, size_t ws_size,
                              hipStream_t stream) {
    const float* x     = (const float*)d_in[0];
    const int*   batch = (const int*)  d_in[1];
    const float* W1    = (const float*)d_in[2];
    const float* b1    = (const float*)d_in[3];
    const float* W2    = (const float*)d_in[4];
    const float* b2    = (const float*)d_in[5];
    float* out = (float*)d_out;

    const int N = in_sizes[1];          // 200000
    const int G = out_size / 256;       // 512

    float* scores = (float*)d_ws;       // N floats scratch

    const int mblocks = (N + TILE_M - 1) / TILE_M;
    scores_kernel<<<mblocks, 256, 0, stream>>>(x, W1, b1, W2, b2, scores, N);
    segpool_kernel<<<G, 1024, 0, stream>>>(x, batch, scores, out, N);
}

// Round 4
// 399.846 us; speedup vs baseline: 1.1309x; 1.1022x over previous
//
#include <hip/hip_runtime.h>
#include <math.h>

// AttentionPooling: scores = tanh(x@W1+b1)@W2+b2; segment softmax over sorted
// `batch`; out[g,:] = sum_i w_i * x[i,:].
// N = in_sizes[1] (200000), D = 256, H = 128, G = out_size/256 (512).
//
// scores via split-bf16 MFMA: x = xh + xl, W1 = wh + wl (RNE bf16 each);
// acc += xh*wh + xh*wl + xl*wh  (fp32 accum) ~= fp32 GEMM to ~2^-17 rel.

typedef __attribute__((ext_vector_type(4))) float f32x4;
typedef __attribute__((ext_vector_type(8))) short s16x8;

#define MFMA16(A, B, C) __builtin_amdgcn_mfma_f32_16x16x32_bf16((A), (B), (C), 0, 0, 0)

__device__ __forceinline__ unsigned short f2bf_rne(float f) {
    unsigned int u = __float_as_uint(f);
    unsigned int r = u + 0x7FFFu + ((u >> 16) & 1u);
    return (unsigned short)(r >> 16);
}
__device__ __forceinline__ float bf2f(unsigned short h) {
    return __uint_as_float(((unsigned int)h) << 16);
}

#define APITCH 36   // fp32 elems per A row (32 + 4 pad); 144B stride, 16B-aligned
#define BPITCH 40   // bf16 elems per B row (32 + 8 pad); 80B stride, 16B-aligned

__global__ __launch_bounds__(256)
void scores_mfma(const float* __restrict__ x, const float* __restrict__ W1,
                 const float* __restrict__ b1, const float* __restrict__ W2,
                 const float* __restrict__ b2, float* __restrict__ scores, int N)
{
    __shared__ __align__(16) float Afp[128 * APITCH];          // x tile, fp32
    __shared__ __align__(16) unsigned short Bhi[128 * BPITCH]; // W1^T hi, [n][k]
    __shared__ __align__(16) unsigned short Blo[128 * BPITCH]; // W1^T lo

    const int tid  = threadIdx.x;
    const int wave = tid >> 6;
    const int lane = tid & 63;
    const int c    = lane & 15;   // col-within-tile / row-within-A-frag
    const int q    = lane >> 4;   // k-quad
    const int rowBase = blockIdx.x * 128;

    f32x4 acc[2][8];
#pragma unroll
    for (int mt = 0; mt < 2; ++mt)
#pragma unroll
        for (int nt = 0; nt < 8; ++nt)
            acc[mt][nt] = (f32x4){0.f, 0.f, 0.f, 0.f};

    const int nB   = tid & 127;   // B-staging: column of W1 this thread owns
    const int half = tid >> 7;    // which 16 of the 32 k's

    for (int k0 = 0; k0 < 256; k0 += 32) {
        __syncthreads();   // protect LDS from previous iteration's readers
        // ---- stage A: x[rowBase..+127][k0..+31] fp32 -> LDS ----
#pragma unroll
        for (int i = 0; i < 4; ++i) {
            int idx = tid + 256 * i;      // 0..1023
            int r   = idx >> 3;           // 0..127
            int c4  = idx & 7;            // float4 chunk within 32
            int row = rowBase + r;
            f32x4 v = (f32x4){0.f, 0.f, 0.f, 0.f};
            if (row < N)
                v = *(const f32x4*)(x + (size_t)row * 256 + k0 + c4 * 4);
            *(f32x4*)&Afp[r * APITCH + c4 * 4] = v;
        }
        // ---- stage B: W1[k0..+31][n] -> split bf16, transposed [n][k] ----
#pragma unroll
        for (int g = 0; g < 4; ++g) {
            unsigned short hs[4], ls[4];
#pragma unroll
            for (int e = 0; e < 4; ++e) {
                int kk = half * 16 + g * 4 + e;
                float f = W1[(size_t)(k0 + kk) * 128 + nB];
                unsigned short h = f2bf_rne(f);
                hs[e] = h;
                ls[e] = f2bf_rne(f - bf2f(h));
            }
            *(ushort4*)&Bhi[nB * BPITCH + half * 16 + g * 4] =
                make_ushort4(hs[0], hs[1], hs[2], hs[3]);
            *(ushort4*)&Blo[nB * BPITCH + half * 16 + g * 4] =
                make_ushort4(ls[0], ls[1], ls[2], ls[3]);
        }
        __syncthreads();

        // ---- A fragments (convert fp32 -> hi/lo bf16 in-register) ----
        s16x8 ahi[2], alo[2];
#pragma unroll
        for (int mt = 0; mt < 2; ++mt) {
            int m = wave * 32 + mt * 16 + c;
            f32x4 a0 = *(const f32x4*)&Afp[m * APITCH + q * 8];
            f32x4 a1 = *(const f32x4*)&Afp[m * APITCH + q * 8 + 4];
            float av[8] = {a0.x, a0.y, a0.z, a0.w, a1.x, a1.y, a1.z, a1.w};
#pragma unroll
            for (int j = 0; j < 8; ++j) {
                unsigned short h = f2bf_rne(av[j]);
                ahi[mt][j] = (short)h;
                alo[mt][j] = (short)f2bf_rne(av[j] - bf2f(h));
            }
        }
        // ---- MFMA over the 8 col-tiles ----
#pragma unroll
        for (int nt = 0; nt < 8; ++nt) {
            int nr = nt * 16 + c;
            s16x8 bh = *(const s16x8*)&Bhi[nr * BPITCH + q * 8];
            s16x8 bl = *(const s16x8*)&Blo[nr * BPITCH + q * 8];
#pragma unroll
            for (int mt = 0; mt < 2; ++mt) {
                acc[mt][nt] = MFMA16(ahi[mt], bh, acc[mt][nt]);
                acc[mt][nt] = MFMA16(ahi[mt], bl, acc[mt][nt]);
                acc[mt][nt] = MFMA16(alo[mt], bh, acc[mt][nt]);
            }
        }
    }

    // ---- epilogue: tanh, dot W2, width-16 reduce, store ----
    float b1v[8], w2v[8];
#pragma unroll
    for (int nt = 0; nt < 8; ++nt) {
        b1v[nt] = b1[nt * 16 + c];
        w2v[nt] = W2[nt * 16 + c];
    }
    const float bias2 = b2[0];

#pragma unroll
    for (int mt = 0; mt < 2; ++mt) {
#pragma unroll
        for (int reg = 0; reg < 4; ++reg) {
            float p = 0.f;
#pragma unroll
            for (int nt = 0; nt < 8; ++nt) {
                float v = acc[mt][nt][reg] + b1v[nt];
                float e = __expf(2.f * v);       // tanh(v) = 1 - 2/(e^{2v}+1)
                p += (1.f - 2.f / (e + 1.f)) * w2v[nt];
            }
#pragma unroll
            for (int off = 8; off > 0; off >>= 1)
                p += __shfl_xor(p, off, 16);
            if (c == 0) {
                int row = rowBase + wave * 32 + mt * 16 + q * 4 + reg;
                if (row < N) scores[row] = p + bias2;
            }
        }
    }
}

__device__ __forceinline__ int lower_bound_dev(const int* __restrict__ b, int n, int v)
{
    int lo = 0, hi = n;
    while (lo < hi) {
        int mid = (lo + hi) >> 1;
        if (b[mid] < v) lo = mid + 1; else hi = mid;
    }
    return lo;
}

// One 1024-thread block per segment. thread = (rslot 0..15, fidx 0..63);
// 16 rows in flight, float4 per lane (wave = 1KB contiguous row slice).
__global__ __launch_bounds__(1024)
void segpool_kernel(const float* __restrict__ x, const int* __restrict__ batch,
                    const float* __restrict__ scores, float* __restrict__ out, int N)
{
    const int g = blockIdx.x;
    const int tid = threadIdx.x;        // 0..1023
    const int fidx  = tid & 63;         // feature group (4 floats)
    const int rslot = tid >> 6;         // 0..15

    __shared__ int se[2];
    __shared__ float sred[1024];        // reductions + weight chunk buffer
    __shared__ float4 rbuf[16][64];     // rowslot partials

    if (tid < 2) se[tid] = lower_bound_dev(batch, N, g + tid);
    __syncthreads();
    const int start = se[0], end = se[1];

    // pass 1: segment max
    float m = -INFINITY;
    for (int i = start + tid; i < end; i += 1024) m = fmaxf(m, scores[i]);
#pragma unroll
    for (int off = 32; off > 0; off >>= 1) m = fmaxf(m, __shfl_xor(m, off, 64));
    if ((tid & 63) == 0) sred[tid >> 6] = m;
    __syncthreads();
    if (tid < 16) {
        float v = sred[tid];
#pragma unroll
        for (int off = 8; off > 0; off >>= 1) v = fmaxf(v, __shfl_xor(v, off, 16));
        if (tid == 0) sred[0] = v;
    }
    __syncthreads();
    m = sred[0];
    __syncthreads();

    // pass 2: denom
    float ssum = 0.f;
    for (int i = start + tid; i < end; i += 1024) ssum += expf(scores[i] - m);
#pragma unroll
    for (int off = 32; off > 0; off >>= 1) ssum += __shfl_xor(ssum, off, 64);
    if ((tid & 63) == 0) sred[tid >> 6] = ssum;
    __syncthreads();
    if (tid < 16) {
        float v = sred[tid];
#pragma unroll
        for (int off = 8; off > 0; off >>= 1) v += __shfl_xor(v, off, 16);
        if (tid == 0) sred[0] = v;
    }
    __syncthreads();
    const float denom = sred[0];
    const float inv = (denom > 0.f) ? 1.f / denom : 0.f;

    // pass 3: weighted sum; chunk weights into LDS, 16 rows in flight
    float4 acc = make_float4(0.f, 0.f, 0.f, 0.f);
    for (int base = start; base < end; base += 1024) {
        int cnt = min(1024, end - base);
        __syncthreads();
        if (tid < cnt) sred[tid] = expf(scores[base + tid] - m) * inv;
        __syncthreads();
#pragma unroll 2
        for (int j = rslot; j < cnt; j += 16) {
            float w = sred[j];
            float4 v = *(const float4*)(x + (size_t)(base + j) * 256 + fidx * 4);
            acc.x = fmaf(w, v.x, acc.x);
            acc.y = fmaf(w, v.y, acc.y);
            acc.z = fmaf(w, v.z, acc.z);
            acc.w = fmaf(w, v.w, acc.w);
        }
    }

    // reduce 16 rowslot partials per feature group
    rbuf[rslot][fidx] = acc;
    __syncthreads();
#pragma unroll
    for (int s = 8; s > 0; s >>= 1) {
        if (rslot < s) {
            float4 o = rbuf[rslot + s][fidx];
            acc.x += o.x; acc.y += o.y; acc.z += o.z; acc.w += o.w;
            rbuf[rslot][fidx] = acc;
        }
        __syncthreads();
    }
    if (rslot == 0)
        ((float4*)out)[(size_t)g * 64 + fidx] = acc;
}

extern "C" void kernel_launch(void* const* d_in, const int* in_sizes, int n_in,
                              void* d_out, int out_size, void* d_ws, size_t ws_size,
                              hipStream_t stream) {
    const float* x     = (const float*)d_in[0];
    const int*   batch = (const int*)  d_in[1];
    const float* W1    = (const float*)d_in[2];
    const float* b1    = (const float*)d_in[3];
    const float* W2    = (const float*)d_in[4];
    const float* b2    = (const float*)d_in[5];
    float* out = (float*)d_out;

    const int N = in_sizes[1];          // 200000
    const int G = out_size / 256;       // 512

    float* scores = (float*)d_ws;       // N floats scratch

    const int mblocks = (N + 127) / 128;
    scores_mfma<<<mblocks, 256, 0, stream>>>(x, W1, b1, W2, b2, scores, N);
    segpool_kernel<<<G, 1024, 0, stream>>>(x, batch, scores, out, N);
}

// Round 5
// 360.327 us; speedup vs baseline: 1.2549x; 1.1097x over previous
//
#include <hip/hip_runtime.h>
#include <hip/hip_bf16.h>
#include <math.h>

// AttentionPooling: scores = tanh(x@W1+b1)@W2+b2; segment softmax over sorted
// `batch`; out[g,:] = sum_i w_i * x[i,:].
// N = in_sizes[1] (200000), D = 256, H = 128, G = out_size/256 (512).
//
// scores via split-bf16 MFMA: x = xh + xl, W1 = wh + wl (RNE bf16 each);
// acc += xh*wh + xh*wl + xl*wh (fp32 accum) ~= fp32 GEMM to ~2^-17 rel.
// W1 split precomputed once (prep_w1) into d_out-as-scratch (segpool
// overwrites d_out afterwards; same-stream ordering makes this safe).

typedef __attribute__((ext_vector_type(4))) float f32x4;
typedef __attribute__((ext_vector_type(8))) short s16x8;
typedef __attribute__((ext_vector_type(8))) unsigned short u16x8;

#define MFMA16(A, B, C) __builtin_amdgcn_mfma_f32_16x16x32_bf16((A), (B), (C), 0, 0, 0)

__device__ __forceinline__ unsigned short f2bf_rne(float f) {
    unsigned int u = __float_as_uint(f);
    unsigned int r = u + 0x7FFFu + ((u >> 16) & 1u);
    return (unsigned short)(r >> 16);
}
__device__ __forceinline__ float bf2f(unsigned short h) {
    return __uint_as_float(((unsigned int)h) << 16);
}

// ---- prep: split W1[k][n] (256x128 fp32) into bh/bl[n][k] (128x256 bf16) ----
__global__ __launch_bounds__(256)
void prep_w1(const float* __restrict__ W1, unsigned short* __restrict__ bh,
             unsigned short* __restrict__ bl)
{
    for (int idx = blockIdx.x * 256 + threadIdx.x; idx < 128 * 256;
         idx += gridDim.x * 256) {
        int n = idx & 127, k = idx >> 7;          // reads coalesced over n
        float f = W1[(size_t)k * 128 + n];
        unsigned short h = f2bf_rne(f);
        bh[(size_t)n * 256 + k] = h;
        bl[(size_t)n * 256 + k] = f2bf_rne(f - bf2f(h));
    }
}

#define LPITCH 40   // bf16 elems per LDS row (32 + 8 pad); 80B stride, 16B-aligned

__global__ __launch_bounds__(256, 3)
void scores_mfma(const float* __restrict__ x,
                 const unsigned short* __restrict__ bh,
                 const unsigned short* __restrict__ bl,
                 const float* __restrict__ b1, const float* __restrict__ W2,
                 const float* __restrict__ b2, float* __restrict__ scores, int N)
{
    __shared__ __align__(16) unsigned short Ahi[128 * LPITCH];
    __shared__ __align__(16) unsigned short Alo[128 * LPITCH];
    __shared__ __align__(16) unsigned short Bhi[128 * LPITCH];
    __shared__ __align__(16) unsigned short Blo[128 * LPITCH];

    const int tid  = threadIdx.x;
    const int wave = tid >> 6;
    const int lane = tid & 63;
    const int c    = lane & 15;   // col-within-tile / row-within-A-frag
    const int q    = lane >> 4;   // k-quad
    const int rowBase = blockIdx.x * 128;

    f32x4 acc[2][8];
#pragma unroll
    for (int mt = 0; mt < 2; ++mt)
#pragma unroll
        for (int nt = 0; nt < 8; ++nt)
            acc[mt][nt] = (f32x4){0.f, 0.f, 0.f, 0.f};

    // staging geometry
    const int arow  = rowBase + (tid >> 1);   // A: 2 threads per row
    const int ak16  = (tid & 1) * 16;         // which 16-k half
    const int nB    = tid & 127;              // B: thread's W1 column
    const int bk16  = (tid >> 7) * 16;        // which 16-k half

    // prefetch registers
    f32x4 pa0, pa1, pa2, pa3;
    u16x8 pb0, pb1, pl0, pl1;

    auto loadA = [&](int k0) {
        if (arow < N) {
            const float* p = x + (size_t)arow * 256 + k0 + ak16;
            pa0 = *(const f32x4*)(p);
            pa1 = *(const f32x4*)(p + 4);
            pa2 = *(const f32x4*)(p + 8);
            pa3 = *(const f32x4*)(p + 12);
        } else {
            pa0 = pa1 = pa2 = pa3 = (f32x4){0.f, 0.f, 0.f, 0.f};
        }
    };
    auto loadB = [&](int k0) {
        const size_t base = (size_t)nB * 256 + k0 + bk16;
        pb0 = *(const u16x8*)(bh + base);
        pb1 = *(const u16x8*)(bh + base + 8);
        pl0 = *(const u16x8*)(bl + base);
        pl1 = *(const u16x8*)(bl + base + 8);
    };

    loadA(0);
    loadB(0);

    for (int it = 0; it < 8; ++it) {
        // ---- convert prefetched A (waits on pa) ----
        float af[16];
        *(f32x4*)&af[0]  = pa0; *(f32x4*)&af[4]  = pa1;
        *(f32x4*)&af[8]  = pa2; *(f32x4*)&af[12] = pa3;
        unsigned short ah[16], al[16];
#pragma unroll
        for (int j = 0; j < 8; ++j) {
            float a0 = af[2 * j], a1 = af[2 * j + 1];
            __hip_bfloat162 h2 = __float22bfloat162_rn(make_float2(a0, a1));
            ushort2 hu = *(ushort2*)&h2;
            float r0 = a0 - bf2f(hu.x), r1 = a1 - bf2f(hu.y);
            __hip_bfloat162 l2 = __float22bfloat162_rn(make_float2(r0, r1));
            ushort2 lu = *(ushort2*)&l2;
            ah[2 * j] = hu.x; ah[2 * j + 1] = hu.y;
            al[2 * j] = lu.x; al[2 * j + 1] = lu.y;
        }

        __syncthreads();   // previous iteration's frag readers are done
        {
            const int ar = tid >> 1;
            *(u16x8*)&Ahi[ar * LPITCH + ak16 + 0] = *(u16x8*)&ah[0];
            *(u16x8*)&Ahi[ar * LPITCH + ak16 + 8] = *(u16x8*)&ah[8];
            *(u16x8*)&Alo[ar * LPITCH + ak16 + 0] = *(u16x8*)&al[0];
            *(u16x8*)&Alo[ar * LPITCH + ak16 + 8] = *(u16x8*)&al[8];
            *(u16x8*)&Bhi[nB * LPITCH + bk16 + 0] = pb0;   // waits on pb
            *(u16x8*)&Bhi[nB * LPITCH + bk16 + 8] = pb1;
            *(u16x8*)&Blo[nB * LPITCH + bk16 + 0] = pl0;
            *(u16x8*)&Blo[nB * LPITCH + bk16 + 8] = pl1;
        }
        __syncthreads();

        // ---- issue next tile's global loads; they drain during MFMA ----
        if (it < 7) {
            loadA((it + 1) * 32);
            loadB((it + 1) * 32);
        }

        // ---- fragments + MFMA ----
        s16x8 fah[2], fal[2];
#pragma unroll
        for (int mt = 0; mt < 2; ++mt) {
            int m = wave * 32 + mt * 16 + c;
            fah[mt] = *(const s16x8*)&Ahi[m * LPITCH + q * 8];
            fal[mt] = *(const s16x8*)&Alo[m * LPITCH + q * 8];
        }
#pragma unroll
        for (int nt = 0; nt < 8; ++nt) {
            int nr = nt * 16 + c;
            s16x8 fbh = *(const s16x8*)&Bhi[nr * LPITCH + q * 8];
            s16x8 fbl = *(const s16x8*)&Blo[nr * LPITCH + q * 8];
#pragma unroll
            for (int mt = 0; mt < 2; ++mt) {
                acc[mt][nt] = MFMA16(fah[mt], fbh, acc[mt][nt]);
                acc[mt][nt] = MFMA16(fah[mt], fbl, acc[mt][nt]);
                acc[mt][nt] = MFMA16(fal[mt], fbh, acc[mt][nt]);
            }
        }
    }

    // ---- epilogue: tanh, dot W2, width-16 reduce, store ----
    float b1v[8], w2v[8];
#pragma unroll
    for (int nt = 0; nt < 8; ++nt) {
        b1v[nt] = b1[nt * 16 + c];
        w2v[nt] = W2[nt * 16 + c];
    }
    const float bias2 = b2[0];

#pragma unroll
    for (int mt = 0; mt < 2; ++mt) {
#pragma unroll
        for (int reg = 0; reg < 4; ++reg) {
            float p = 0.f;
#pragma unroll
            for (int nt = 0; nt < 8; ++nt) {
                float v = acc[mt][nt][reg] + b1v[nt];
                float e = __expf(2.f * v);       // tanh(v) = 1 - 2/(e^{2v}+1)
                p += (1.f - 2.f / (e + 1.f)) * w2v[nt];
            }
#pragma unroll
            for (int off = 8; off > 0; off >>= 1)
                p += __shfl_xor(p, off, 16);
            if (c == 0) {
                int row = rowBase + wave * 32 + mt * 16 + q * 4 + reg;
                if (row < N) scores[row] = p + bias2;
            }
        }
    }
}

__device__ __forceinline__ int lower_bound_dev(const int* __restrict__ b, int n, int v)
{
    int lo = 0, hi = n;
    while (lo < hi) {
        int mid = (lo + hi) >> 1;
        if (b[mid] < v) lo = mid + 1; else hi = mid;
    }
    return lo;
}

// One 1024-thread block per segment. thread = (rslot 0..15, fidx 0..63);
// 16 rows in flight, float4 per lane.
__global__ __launch_bounds__(1024)
void segpool_kernel(const float* __restrict__ x, const int* __restrict__ batch,
                    const float* __restrict__ scores, float* __restrict__ out, int N)
{
    const int g = blockIdx.x;
    const int tid = threadIdx.x;        // 0..1023
    const int fidx  = tid & 63;         // feature group (4 floats)
    const int rslot = tid >> 6;         // 0..15

    __shared__ int se[2];
    __shared__ float sred[1024];        // reductions + weight chunk buffer
    __shared__ float4 rbuf[16][64];     // rowslot partials

    if (tid < 2) se[tid] = lower_bound_dev(batch, N, g + tid);
    __syncthreads();
    const int start = se[0], end = se[1];

    // pass 1: segment max
    float m = -INFINITY;
    for (int i = start + tid; i < end; i += 1024) m = fmaxf(m, scores[i]);
#pragma unroll
    for (int off = 32; off > 0; off >>= 1) m = fmaxf(m, __shfl_xor(m, off, 64));
    if ((tid & 63) == 0) sred[tid >> 6] = m;
    __syncthreads();
    if (tid < 16) {
        float v = sred[tid];
#pragma unroll
        for (int off = 8; off > 0; off >>= 1) v = fmaxf(v, __shfl_xor(v, off, 16));
        if (tid == 0) sred[0] = v;
    }
    __syncthreads();
    m = sred[0];
    __syncthreads();

    // pass 2: denom
    float ssum = 0.f;
    for (int i = start + tid; i < end; i += 1024) ssum += expf(scores[i] - m);
#pragma unroll
    for (int off = 32; off > 0; off >>= 1) ssum += __shfl_xor(ssum, off, 64);
    if ((tid & 63) == 0) sred[tid >> 6] = ssum;
    __syncthreads();
    if (tid < 16) {
        float v = sred[tid];
#pragma unroll
        for (int off = 8; off > 0; off >>= 1) v += __shfl_xor(v, off, 16);
        if (tid == 0) sred[0] = v;
    }
    __syncthreads();
    const float denom = sred[0];
    const float inv = (denom > 0.f) ? 1.f / denom : 0.f;

    // pass 3: weighted sum; chunk weights into LDS, 16 rows in flight
    float4 acc = make_float4(0.f, 0.f, 0.f, 0.f);
    for (int base = start; base < end; base += 1024) {
        int cnt = min(1024, end - base);
        __syncthreads();
        if (tid < cnt) sred[tid] = expf(scores[base + tid] - m) * inv;
        __syncthreads();
#pragma unroll 2
        for (int j = rslot; j < cnt; j += 16) {
            float w = sred[j];
            float4 v = *(const float4*)(x + (size_t)(base + j) * 256 + fidx * 4);
            acc.x = fmaf(w, v.x, acc.x);
            acc.y = fmaf(w, v.y, acc.y);
            acc.z = fmaf(w, v.z, acc.z);
            acc.w = fmaf(w, v.w, acc.w);
        }
    }

    // reduce 16 rowslot partials per feature group
    rbuf[rslot][fidx] = acc;
    __syncthreads();
#pragma unroll
    for (int s = 8; s > 0; s >>= 1) {
        if (rslot < s) {
            float4 o = rbuf[rslot + s][fidx];
            acc.x += o.x; acc.y += o.y; acc.z += o.z; acc.w += o.w;
            rbuf[rslot][fidx] = acc;
        }
        __syncthreads();
    }
    if (rslot == 0)
        ((float4*)out)[(size_t)g * 64 + fidx] = acc;
}

extern "C" void kernel_launch(void* const* d_in, const int* in_sizes, int n_in,
                              void* d_out, int out_size, void* d_ws, size_t ws_size,
                              hipStream_t stream) {
    const float* x     = (const float*)d_in[0];
    const int*   batch = (const int*)  d_in[1];
    const float* W1    = (const float*)d_in[2];
    const float* b1    = (const float*)d_in[3];
    const float* W2    = (const float*)d_in[4];
    const float* b2    = (const float*)d_in[5];
    float* out = (float*)d_out;

    const int N = in_sizes[1];          // 200000
    const int G = out_size / 256;       // 512

    float* scores = (float*)d_ws;       // N floats scratch (proven-fit in ws)

    // W1 split lives in d_out-as-scratch (128 KB of the 512 KB output buffer);
    // segpool overwrites d_out afterwards — same-stream ordering makes it safe.
    unsigned short* bh = (unsigned short*)d_out;
    unsigned short* bl = bh + 128 * 256;

    prep_w1<<<64, 256, 0, stream>>>(W1, bh, bl);
    const int mblocks = (N + 127) / 128;
    scores_mfma<<<mblocks, 256, 0, stream>>>(x, bh, bl, b1, W2, b2, scores, N);
    segpool_kernel<<<G, 1024, 0, stream>>>(x, batch, scores, out, N);
}